// Round 4
// baseline (932.538 us; speedup 1.0000x reference)
//
#include <hip/hip_runtime.h>

#define TOKENS 8192
#define KDIM   4096
#define OUTF   11008
#define NTILE  64            // 4096 / 64-byte K-tiles

typedef int   int4v   __attribute__((ext_vector_type(4)));
typedef float float4v __attribute__((ext_vector_type(4)));

// ---------------- kernel 1: fused prep ----------------
// blocks [0, TOKENS)          : per-token dynamic asymmetric int8 quant of x
// blocks [TOKENS, TOKENS+OUTF): repack int32 weight -> int8 + row sums
// Fused so the two independent streams execute CONCURRENTLY (they were
// sequential launches = sum of durations). Inputs x / w are single-use ->
// nontemporal loads (don't evict q8/w8 from L3; the GEMM wants those hot).
// q8/w8 stores stay CACHED on purpose - they seed L3 for the GEMM.
// NOTE: NT builtins require ext_vector_type pointers (HIP_vector_type like
// int4/float4 is a class -> compile error).
__global__ __launch_bounds__(256) void prep_kernel(
    const float* __restrict__ x, char* __restrict__ q8,
    float* __restrict__ sc, float* __restrict__ zpv, int* __restrict__ qsum,
    const int* __restrict__ w, char* __restrict__ w8, int* __restrict__ wsum)
{
    const int tid = threadIdx.x;
    __shared__ float smn[4], smx[4];
    __shared__ int ssum[4];

    if (blockIdx.x >= TOKENS) {
        // ---------- pack path: one weight row per block ----------
        const int o = blockIdx.x - TOKENS;
        const int4v* wr = (const int4v*)(w + (size_t)o * KDIM) + (size_t)tid * 4;
        int4v a[4];
#pragma unroll
        for (int j = 0; j < 4; ++j) a[j] = __builtin_nontemporal_load(wr + j);
        int s = 0;
        int4v pk;
#pragma unroll
        for (int j = 0; j < 4; ++j) {
            s += a[j].x + a[j].y + a[j].z + a[j].w;
            pk[j] = (a[j].x & 255) | ((a[j].y & 255) << 8) |
                    ((a[j].z & 255) << 16) | (a[j].w << 24);
        }
        ((int4v*)(w8 + (size_t)o * KDIM))[tid] = pk;  // cached: GEMM reads this
#pragma unroll
        for (int off = 32; off > 0; off >>= 1) s += __shfl_down(s, off, 64);
        if ((tid & 63) == 0) ssum[tid >> 6] = s;
        __syncthreads();
        if (tid == 0) wsum[o] = ssum[0] + ssum[1] + ssum[2] + ssum[3];
        return;
    }

    // ---------- quant path: one token row per block ----------
    const int t = blockIdx.x;
    const float4v* xr = (const float4v*)(x + (size_t)t * KDIM) + (size_t)tid * 4;

    float4v v[4];
    float mn = 3.0e38f, mx = -3.0e38f;
#pragma unroll
    for (int j = 0; j < 4; ++j) {
        v[j] = __builtin_nontemporal_load(xr + j);
        mn = fminf(mn, fminf(fminf(v[j].x, v[j].y), fminf(v[j].z, v[j].w)));
        mx = fmaxf(mx, fmaxf(fmaxf(v[j].x, v[j].y), fmaxf(v[j].z, v[j].w)));
    }
#pragma unroll
    for (int off = 32; off > 0; off >>= 1) {
        mn = fminf(mn, __shfl_down(mn, off, 64));
        mx = fmaxf(mx, __shfl_down(mx, off, 64));
    }
    if ((tid & 63) == 0) { smn[tid >> 6] = mn; smx[tid >> 6] = mx; }
    __syncthreads();
    mn = fminf(fminf(smn[0], smn[1]), fminf(smn[2], smn[3]));
    mx = fmaxf(fmaxf(smx[0], smx[1]), fmaxf(smx[2], smx[3]));

    const float min_neg = fminf(mn, 0.0f);
    const float max_pos = fmaxf(mx, 0.0f);
    float scale = (max_pos - min_neg) / 255.0f;
    scale = fmaxf(scale, 1.1920928955078125e-07f);  // FLT_EPSILON
    const float dmin = min_neg / scale;
    const float dmax = max_pos / scale;
    float zpf = ((-128.0f + dmin) + (127.0f + dmax) > 0.0f) ? (-128.0f - dmin)
                                                            : (127.0f - dmax);
    zpf = fminf(fmaxf(rintf(zpf), -128.0f), 127.0f);
    const float inv = 1.0f / scale;

    int s = 0;
    int4v pk;
#pragma unroll
    for (int j = 0; j < 4; ++j) {
        int q0 = (int)fminf(fmaxf(rintf(v[j].x * inv) + zpf, -128.0f), 127.0f);
        int q1 = (int)fminf(fmaxf(rintf(v[j].y * inv) + zpf, -128.0f), 127.0f);
        int q2 = (int)fminf(fmaxf(rintf(v[j].z * inv) + zpf, -128.0f), 127.0f);
        int q3 = (int)fminf(fmaxf(rintf(v[j].w * inv) + zpf, -128.0f), 127.0f);
        s += q0 + q1 + q2 + q3;
        pk[j] = (q0 & 255) | ((q1 & 255) << 8) | ((q2 & 255) << 16) | (q3 << 24);
    }
    ((int4v*)(q8 + (size_t)t * KDIM))[tid] = pk;      // cached: GEMM reads this
#pragma unroll
    for (int off = 32; off > 0; off >>= 1) s += __shfl_down(s, off, 64);
    if ((tid & 63) == 0) ssum[tid >> 6] = s;
    __syncthreads();
    if (tid == 0) {
        sc[t] = scale;
        zpv[t] = zpf;
        qsum[t] = ssum[0] + ssum[1] + ssum[2] + ssum[3];
    }
}

// ---------------- kernel 2: int8 GEMM, 256x256 tile, ring-4 deep pipeline ----------------
// Unchanged schedule from the 445 us version (depth-3 counted vmcnt(8), one raw
// s_barrier + sched_barrier(0) per K-tile, XOR-swizzled LDS, XCD swizzle).
// NEW: nontemporal epilogue stores. The 360 MB fp32 output stream was flowing
// through L3 and evicting the q8+w8 panels (78 MB, which fit entirely in the
// 256 MB L3) -> 760 MB HBM FETCH/dispatch. NT stores keep the panels resident;
// predicted FETCH -> 150-250 MB and the vmcnt(8) waits collapse.
__device__ __forceinline__ void async_cp16(const void* g, void* l) {
    __builtin_amdgcn_global_load_lds(
        (const __attribute__((address_space(1))) void*)g,
        (__attribute__((address_space(3))) void*)l, 16, 0, 0);
}

#define STAGE(T)                                                                \
    do {                                                                        \
        char* dA_ = smem + ((T) & 3) * 32768;                                   \
        char* dB_ = dA_ + 16384;                                                \
        const int k0_ = (T) * 64;                                               \
        _Pragma("unroll")                                                       \
        for (int it_ = 0; it_ < 2; ++it_) {                                     \
            const int idx_ = it_ * 512 + tid;                                   \
            const int r_ = idx_ >> 2;                                           \
            const int cs_ = (((idx_ & 3) ^ ((r_ >> 1) & 3)) << 4);              \
            async_cp16(Ag + (size_t)r_ * KDIM + k0_ + cs_, dA_ + idx_ * 16);    \
            async_cp16(Bg + (size_t)r_ * KDIM + k0_ + cs_, dB_ + idx_ * 16);    \
        }                                                                       \
    } while (0)

#define COMPUTE(T)                                                              \
    do {                                                                        \
        const char* sA_ = smem + ((T) & 3) * 32768;                             \
        const char* sB_ = sA_ + 16384;                                          \
        int4v a_[8], b_[4];                                                     \
        _Pragma("unroll")                                                       \
        for (int mi_ = 0; mi_ < 8; ++mi_)                                       \
            a_[mi_] = *(const int4v*)(sA_ + (wm + mi_ * 16 + lr) * 64 + coff);  \
        _Pragma("unroll")                                                       \
        for (int ni_ = 0; ni_ < 4; ++ni_)                                       \
            b_[ni_] = *(const int4v*)(sB_ + (wn + ni_ * 16 + lr) * 64 + coff);  \
        __builtin_amdgcn_s_setprio(1);                                          \
        _Pragma("unroll")                                                       \
        for (int mi_ = 0; mi_ < 8; ++mi_)                                       \
            _Pragma("unroll")                                                   \
            for (int ni_ = 0; ni_ < 4; ++ni_)                                   \
                acc[mi_][ni_] = __builtin_amdgcn_mfma_i32_16x16x64_i8(          \
                    a_[mi_], b_[ni_], acc[mi_][ni_], 0, 0, 0);                  \
        __builtin_amdgcn_s_setprio(0);                                          \
    } while (0)

#define WAIT_BAR(N)                                                             \
    asm volatile("s_waitcnt vmcnt(" #N ")" ::: "memory");                       \
    __builtin_amdgcn_s_barrier();                                               \
    __builtin_amdgcn_sched_barrier(0);

__global__ __launch_bounds__(512, 2) void gemm_i8_kernel(
    const char* __restrict__ q8, const char* __restrict__ w8,
    const float* __restrict__ sc, const float* __restrict__ zpv,
    const int* __restrict__ qsum,
    const float* __restrict__ scales, const float* __restrict__ zeros,
    const int* __restrict__ wsum, float* __restrict__ out)
{
    const int tid = threadIdx.x;
    const int wave = tid >> 6;
    const int lane = tid & 63;

    // T1: XCD-aware swizzle. 1376 blocks % 8 == 0 -> simple bijective remap.
    const int bid = blockIdx.x;
    const int swz = (bid & 7) * 172 + (bid >> 3);
    const int by = swz / 43;            // M tile 0..31
    const int bx = swz - by * 43;       // N tile 0..42
    const int t0 = by * 256;
    const int o0 = bx * 256;

    __shared__ char smem[131072];       // 4 slots x 32 KB

    const char* Ag = q8 + (size_t)t0 * KDIM;
    const char* Bg = w8 + (size_t)o0 * KDIM;

    const int wm = (wave >> 2) * 128;   // 2 wave-rows of 128
    const int wn = (wave & 3) * 64;     // 4 wave-cols of 64
    const int lr = lane & 15;
    const int kq = lane >> 4;                       // 16B chunk of the 64B K-slice
    const int coff = ((kq ^ ((lr >> 1) & 3)) << 4); // swizzled LDS chunk (lane-const)

    int4v acc[8][4];
#pragma unroll
    for (int mi = 0; mi < 8; ++mi)
#pragma unroll
        for (int ni = 0; ni < 4; ++ni)
            acc[mi][ni] = (int4v){0, 0, 0, 0};

    // prologue: fill pipeline with tiles 0,1,2 (12 loads/wave in flight)
    STAGE(0); STAGE(1); STAGE(2);

    // main loop: wait leaves tiles t+1,t+2 in flight (vmcnt 8)
    for (int t = 0; t < NTILE - 3; ++t) {
        WAIT_BAR(8)
        STAGE(t + 3);
        COMPUTE(t);
    }
    // tail: drain 8 -> 4 -> 0
    WAIT_BAR(8)
    COMPUTE(NTILE - 3);
    WAIT_BAR(4)
    COMPUTE(NTILE - 2);
    WAIT_BAR(0)
    COMPUTE(NTILE - 1);

    // epilogue: out[t,o] = st*so*( dot - zp_t*Wsum_o - z_o*(Qsum_t - 4096*zp_t) )
#pragma unroll
    for (int mi = 0; mi < 8; ++mi) {
        const int tb = t0 + wm + mi * 16 + (kq << 2);
        float st4[4], zp4[4], qs4[4];
        int zi4[4];
#pragma unroll
        for (int r = 0; r < 4; ++r) {
            st4[r] = sc[tb + r];
            zp4[r] = zpv[tb + r];
            zi4[r] = (int)zp4[r];
            qs4[r] = (float)qsum[tb + r];
        }
#pragma unroll
        for (int ni = 0; ni < 4; ++ni) {
            const int o = o0 + wn + ni * 16 + lr;
            const float so = scales[o];
            const float zo = zeros[o];
            const long long wso = (long long)wsum[o];
#pragma unroll
            for (int r = 0; r < 4; ++r) {
                long long iv = (long long)acc[mi][ni][r] - (long long)zi4[r] * wso;
                float val = (float)iv - zo * (qs4[r] - 4096.0f * zp4[r]);
                __builtin_nontemporal_store(st4[r] * so * val,
                                            &out[(size_t)(tb + r) * OUTF + o]);
            }
        }
    }
}

// ---------------- launch ----------------
extern "C" void kernel_launch(void* const* d_in, const int* in_sizes, int n_in,
                              void* d_out, int out_size, void* d_ws, size_t ws_size,
                              hipStream_t stream) {
    const float* x      = (const float*)d_in[0];
    const int*   w      = (const int*)d_in[1];
    const float* scales = (const float*)d_in[2];
    const float* zeros  = (const float*)d_in[3];
    float* out = (float*)d_out;

    char* ws = (char*)d_ws;
    char*  q8   = ws;                              // 33554432 B
    char*  w8   = ws + 33554432;                   // 45088768 B
    float* sc   = (float*)(ws + 78643200);
    float* zp   = (float*)(ws + 78675968);
    int*   qsum = (int*)(ws + 78708736);
    int*   wsum = (int*)(ws + 78741504);

    prep_kernel<<<TOKENS + OUTF, 256, 0, stream>>>(x, q8, sc, zp, qsum, w, w8, wsum);
    gemm_i8_kernel<<<dim3(1376), 512, 0, stream>>>(q8, w8, sc, zp, qsum, scales, zeros, wsum, out);
}